// Round 10
// baseline (133.411 us; speedup 1.0000x reference)
//
#include <hip/hip_runtime.h>

// Problem constants
#define SRC_N   (512 * 512)
#define IMG_W   1024
#define IMG_HW  (1024 * 1024)
#define BATCH   4

#define CHUNKS_PER_B   256
#define K1_BLOCKS      (BATCH * CHUNKS_PER_B)    // 1024
#define K1_THREADS     256
#define PTS_PER_CHUNK  1024
// Bins: 0..255 = 4-row bands (y-interior pixels); 256..287 = row-0 px-segments
// (32 px each); 288..319 = row-1023 px-segments. Corners -> LDS side path.
#define NBINS          320
#define SENT           0xFFFFFFFFu

// native vector type for nontemporal builtins (HIP float4 is a class type)
typedef float nfloat4 __attribute__((ext_vector_type(4)));

// ws layout (all tables fully rewritten every call; no memsets needed)
// prefix is TRANSPOSED: [b][bin(0..NBINS)][chunk] so run-bound reads are
// contiguous rows. Column writes from bin_kernel are 4B/line but L2-absorbed
// (pattern proven safe in R6's histcum).
#define STAGED_BYTES ((size_t)K1_BLOCKS * PTS_PER_CHUNK * 16)          // 16 MB
#define PF_OFF       STAGED_BYTES
#define PF_BYTES     ((size_t)BATCH * (NBINS + 1) * CHUNKS_PER_B * 4)  // 1.31 MB
#define CO_OFF       ((PF_OFF + PF_BYTES + 255) & ~(size_t)255)
#define CO_BYTES     ((size_t)K1_BLOCKS * 12 * 4)                      // 48 KB
#define EB_OFF       ((CO_OFF + CO_BYTES + 255) & ~(size_t)255)
// edgebuf: [b][row(2)][c(3)][1024] floats = 96 KB

// ---------------------------------------------------------------------------
// K1: classify + per-chunk bin. 1024 blocks x 256 threads (~4 blocks/CU for
// latency overlap). Pair-scan (2 bins/thread): wave shfl scan + 4 wave
// totals -> 4 barriers. Zero global atomics.
// ---------------------------------------------------------------------------
__global__ void __launch_bounds__(256)
bin_kernel(const float* __restrict__ uv, const float* __restrict__ pos,
           float4* __restrict__ staged, unsigned* __restrict__ prefix,
           float* __restrict__ corner_out) {
    const int blk   = blockIdx.x;          // 0..1023
    const int b     = blk >> 8;
    const int chunk = blk & (CHUNKS_PER_B - 1);
    const int t     = threadIdx.x;
    const int lane  = t & 63;
    const int wave  = t >> 6;              // 0..3

    __shared__ unsigned s_hist[512];       // bins 320..511 stay zero
    __shared__ unsigned s_cur[NBINS];
    __shared__ unsigned s_wsum[4];
    __shared__ float    s_corner[12];

    s_hist[t] = 0; s_hist[t + 256] = 0;
    if (t < 12) s_corner[t] = 0.0f;
    __syncthreads();                                               // B1

    const float* uvb = uv  + (size_t)b * 14 * SRC_N;
    const float* pb  = pos + (size_t)b * 3  * SRC_N;
    const int n0 = chunk * PTS_PER_CHUNK + t * 4;

    const float4 pxv = *(const float4*)&pb [n0];
    const float4 pyv = *(const float4*)&pb [SRC_N + n0];
    const float4 ux  = *(const float4*)&uvb[n0];
    const float4 uy  = *(const float4*)&uvb[SRC_N + n0];
    const float4 ov  = *(const float4*)&uvb[10 * SRC_N + n0];
    const float4 rv  = *(const float4*)&uvb[11 * SRC_N + n0];
    const float4 gv  = *(const float4*)&uvb[12 * SRC_N + n0];
    const float4 bv  = *(const float4*)&uvb[13 * SRC_N + n0];

    const float X[4]  = {pxv.x + ux.x, pxv.y + ux.y, pxv.z + ux.z, pxv.w + ux.w};
    const float Y[4]  = {pyv.x + uy.x, pyv.y + uy.y, pyv.z + uy.z, pyv.w + uy.w};
    const float O[4]  = {ov.x, ov.y, ov.z, ov.w};
    const float CR[4] = {rv.x, rv.y, rv.z, rv.w};
    const float CG[4] = {gv.x, gv.y, gv.z, gv.w};
    const float CB[4] = {bv.x, bv.y, bv.z, bv.w};

    unsigned packed[4];
    float R[4], G[4], B[4];

#pragma unroll
    for (int j = 0; j < 4; ++j) {
        // truncating cast (matches .astype(int32)), then clamp
        int px = (int)((X[j] + 1.0f) * 512.0f);
        int py = (int)((Y[j] + 1.0f) * 512.0f);
        px = min(max(px, 0), IMG_W - 1);
        py = min(max(py, 0), IMG_W - 1);

        const float opac = 1.0f / (1.0f + __expf(-O[j]));
        R[j] = CR[j] * opac; G[j] = CG[j] * opac; B[j] = CB[j] * opac;

        const bool xe = (px == 0) | (px == IMG_W - 1);
        const bool ye = (py == 0) | (py == IMG_W - 1);
        if (xe & ye) {
            const int ci = ((py != 0) ? 2 : 0) + ((px != 0) ? 1 : 0);
            atomicAdd(&s_corner[ci * 3 + 0], R[j]);
            atomicAdd(&s_corner[ci * 3 + 1], G[j]);
            atomicAdd(&s_corner[ci * 3 + 2], B[j]);
            packed[j] = SENT;
        } else {
            int bin;
            if (ye) bin = 256 + ((py != 0) ? 32 : 0) + (px >> 5);  // edge seg
            else    bin = py >> 2;                                 // 4-row band
            atomicAdd(&s_hist[bin], 1u);
            packed[j] = ((unsigned)bin << 12) | ((unsigned)(py & 3) << 10)
                      | (unsigned)px;
        }
    }
    __syncthreads();                                               // B2

    // pair-scan: thread t owns bins 2t, 2t+1
    const unsigned h0 = s_hist[2 * t], h1 = s_hist[2 * t + 1];
    const unsigned pair = h0 + h1;
    unsigned incl = pair;
#pragma unroll
    for (int off = 1; off < 64; off <<= 1) {
        const unsigned n = __shfl_up(incl, off, 64);
        if (lane >= off) incl += n;
    }
    if (lane == 63) s_wsum[wave] = incl;   // wave total
    __syncthreads();                                               // B3
    unsigned woff = 0;
#pragma unroll
    for (int w = 0; w < 4; ++w) woff += (w < wave) ? s_wsum[w] : 0u;
    const unsigned excl = woff + incl - pair;

    unsigned* pfT = prefix + (size_t)b * (NBINS + 1) * CHUNKS_PER_B;
    if (t < NBINS / 2) {                   // t < 160: bins 2t, 2t+1
        s_cur[2 * t]     = excl;
        s_cur[2 * t + 1] = excl + h0;
        pfT[(size_t)(2 * t)     * CHUNKS_PER_B + chunk] = excl;
        pfT[(size_t)(2 * t + 1) * CHUNKS_PER_B + chunk] = excl + h0;
    } else if (t == NBINS / 2) {           // bin 320 row = totals
        pfT[(size_t)NBINS * CHUNKS_PER_B + chunk] = excl;
    }
    if (t < 12) corner_out[blk * 12 + t] = s_corner[t];
    __syncthreads();                                               // B4

    // cur-ordered scatter into the chunk's private staged region
    float4* pbase = staged + (size_t)blk * PTS_PER_CHUNK;
#pragma unroll
    for (int j = 0; j < 4; ++j) {
        if (packed[j] != SENT) {
            const int bin = packed[j] >> 12;
            const unsigned p = atomicAdd(&s_cur[bin], 1u);
            pbase[p] = make_float4(__uint_as_float(packed[j]), R[j], G[j], B[j]);
        }
    }
}

// ---------------------------------------------------------------------------
// K2e: one block per (batch, row in {0,1023}, 32-px segment). Contiguous
// run-bound rows; 1 reader per chunk. Accumulates edge payloads + corner
// partials into 96 floats, stores edgebuf.
// ---------------------------------------------------------------------------
__global__ void __launch_bounds__(256)
edge_kernel(const float4* __restrict__ staged, const unsigned* __restrict__ prefix,
            const float* __restrict__ corner_out, float* __restrict__ edgebuf) {
    const int blk = blockIdx.x;            // b*64 + row*32 + seg
    const int b   = blk >> 6;
    const int row = (blk >> 5) & 1;
    const int seg = blk & 31;
    const int bin = 256 + row * 32 + seg;
    const int t   = threadIdx.x;

    __shared__ float acc[96];              // [c][lx]

    if (t < 96) acc[t] = 0.0f;
    const unsigned* pfT = prefix + (size_t)b * (NBINS + 1) * CHUNKS_PER_B;
    const unsigned s = pfT[(size_t)bin       * CHUNKS_PER_B + t];   // contiguous row
    const unsigned e = pfT[(size_t)(bin + 1) * CHUNKS_PER_B + t];   // contiguous row
    __syncthreads();

    const float4* pbase = staged + (size_t)(b * CHUNKS_PER_B + t) * PTS_PER_CHUNK;
    for (unsigned i = s; i < e; ++i) {
        const float4 v = pbase[i];
        const int lx = (int)(__float_as_uint(v.x) & 1023u) - seg * 32;
        atomicAdd(&acc[lx],      v.y);
        atomicAdd(&acc[32 + lx], v.z);
        atomicAdd(&acc[64 + lx], v.w);
    }

    // corner fold: seg 0 owns px=0, seg 31 owns px=1023 of this row
    if ((seg == 0) | (seg == 31)) {
        const int ci = row * 2 + ((seg == 31) ? 1 : 0);
        const int lx = (seg == 31) ? 31 : 0;
        const float* cp = corner_out + (size_t)(b * CHUNKS_PER_B + t) * 12 + ci * 3;
        atomicAdd(&acc[lx],      cp[0]);
        atomicAdd(&acc[32 + lx], cp[1]);
        atomicAdd(&acc[64 + lx], cp[2]);
    }
    __syncthreads();

    if (t < 96) {
        const int c = t >> 5, lx = t & 31;
        edgebuf[((size_t)(b * 2 + row) * 3 + c) * 1024 + seg * 32 + lx] = acc[c * 32 + lx];
    }
}

// ---------------------------------------------------------------------------
// K2: one 512-thread block per (batch, 4-row band). 48 KB LDS stripe.
// Contiguous run-bound rows (1 KB each); 2 sub-readers per chunk.
// LDS-atomic accumulate, fold edgebuf for bands 0/255, fully linear
// nontemporal clipped float4 stores.
// ---------------------------------------------------------------------------
__global__ void __launch_bounds__(512)
accum_kernel(const float4* __restrict__ staged, const unsigned* __restrict__ prefix,
             const float* __restrict__ edgebuf, float* __restrict__ out) {
    const int bg   = blockIdx.x;           // 0..1023
    const int b    = bg >> 8;
    const int band = bg & 255;
    const int t    = threadIdx.x;

    __shared__ float    acc[3 * 4096];     // [c][ly*1024+px], 48 KB
    __shared__ unsigned rs[CHUNKS_PER_B], re[CHUNKS_PER_B];

    float4* acc4 = (float4*)acc;
    const float4 z4 = make_float4(0.f, 0.f, 0.f, 0.f);
#pragma unroll
    for (int i = 0; i < 6; ++i) acc4[i * 512 + t] = z4;
    const unsigned* pfT = prefix + (size_t)b * (NBINS + 1) * CHUNKS_PER_B;
    if (t < 256) rs[t]       = pfT[(size_t)band       * CHUNKS_PER_B + t];
    else         re[t - 256] = pfT[(size_t)(band + 1) * CHUNKS_PER_B + (t - 256)];
    __syncthreads();

    const int chunk = t & 255;
    const int sub   = t >> 8;              // 0..1
    const float4* pbase = staged + (size_t)(b * CHUNKS_PER_B + chunk) * PTS_PER_CHUNK;
    for (unsigned i = rs[chunk] + sub; i < re[chunk]; i += 2) {
        const float4 v = pbase[i];
        const unsigned key = __float_as_uint(v.x);
        const unsigned idx = ((key >> 10) & 3u) * 1024 + (key & 1023u);
        atomicAdd(&acc[idx],        v.y);
        atomicAdd(&acc[4096 + idx], v.z);
        atomicAdd(&acc[8192 + idx], v.w);
    }
    __syncthreads();

    // fold edge rows: band 0 row ly=0 <- edgebuf row0; band 255 ly=3 <- row1023
    if (band == 0) {
        const float4* eb = (const float4*)(edgebuf + (size_t)(b * 2 + 0) * 3 * 1024);
        for (int k = t; k < 768; k += 512) {
            const int c = k >> 8, q = k & 255;
            const float4 e = eb[k];
            float4 a = acc4[c * 1024 + q];            // ly=0 row
            a.x += e.x; a.y += e.y; a.z += e.z; a.w += e.w;
            acc4[c * 1024 + q] = a;
        }
    } else if (band == 255) {
        const float4* eb = (const float4*)(edgebuf + (size_t)(b * 2 + 1) * 3 * 1024);
        for (int k = t; k < 768; k += 512) {
            const int c = k >> 8, q = k & 255;
            const float4 e = eb[k];
            float4 a = acc4[c * 1024 + 768 + q];      // ly=3 row
            a.x += e.x; a.y += e.y; a.z += e.z; a.w += e.w;
            acc4[c * 1024 + 768 + q] = a;
        }
    }
    __syncthreads();

    // fully linear clipped nontemporal stores
    float* ob = out + (size_t)b * 3 * IMG_HW + (size_t)band * 4096;
#pragma unroll
    for (int c = 0; c < 3; ++c) {
        nfloat4* dst = (nfloat4*)(ob + (size_t)c * IMG_HW);
#pragma unroll
        for (int k = 0; k < 2; ++k) {
            float4 v = acc4[c * 1024 + k * 512 + t];
            nfloat4 w;
            w.x = fminf(fmaxf(v.x, 0.f), 1.f);
            w.y = fminf(fmaxf(v.y, 0.f), 1.f);
            w.z = fminf(fmaxf(v.z, 0.f), 1.f);
            w.w = fminf(fmaxf(v.w, 0.f), 1.f);
            __builtin_nontemporal_store(w, &dst[k * 512 + t]);
        }
    }
}

extern "C" void kernel_launch(void* const* d_in, const int* in_sizes, int n_in,
                              void* d_out, int out_size, void* d_ws, size_t ws_size,
                              hipStream_t stream) {
    const float* uv  = (const float*)d_in[0];   // (4,14,512,512)
    const float* pos = (const float*)d_in[1];   // (4,3,512,512)
    float* out = (float*)d_out;                 // (4,3,1024,1024)

    char* ws = (char*)d_ws;
    float4*   staged     = (float4*)(ws);
    unsigned* prefix     = (unsigned*)(ws + PF_OFF);
    float*    corner_out = (float*)(ws + CO_OFF);
    float*    edgebuf    = (float*)(ws + EB_OFF);

    bin_kernel  <<<K1_BLOCKS, K1_THREADS, 0, stream>>>(uv, pos, staged, prefix,
                                                       corner_out);
    edge_kernel <<<BATCH * 64, 256, 0, stream>>>(staged, prefix, corner_out,
                                                 edgebuf);
    accum_kernel<<<BATCH * 256, 512, 0, stream>>>(staged, prefix, edgebuf, out);
}

// Round 11
// 131.500 us; speedup vs baseline: 1.0145x; 1.0145x over previous
//
#include <hip/hip_runtime.h>

// Problem constants
#define SRC_N   (512 * 512)
#define IMG_W   1024
#define IMG_HW  (1024 * 1024)
#define BATCH   4

#define CHUNKS_PER_B   256
#define K1_BLOCKS      (BATCH * CHUNKS_PER_B)    // 1024
#define K1_THREADS     256
#define PTS_PER_CHUNK  1024
// Bins: 0..255 = 4-row bands (y-interior pixels); 256..287 = row-0 px-segments
// (32 px each); 288..319 = row-1023 px-segments. Corners -> LDS side path.
#define NBINS          320
#define SENT           0xFFFFFFFFu

// native vector type for nontemporal builtins (HIP float4 is a class type)
typedef float nfloat4 __attribute__((ext_vector_type(4)));

// ws layout (all tables fully rewritten every call; no memsets needed)
// prefix is TRANSPOSED: [b][bin(0..NBINS)][chunk] so run-bound reads are
// contiguous rows.
#define STAGED_BYTES ((size_t)K1_BLOCKS * PTS_PER_CHUNK * 16)          // 16 MB
#define PF_OFF       STAGED_BYTES
#define PF_BYTES     ((size_t)BATCH * (NBINS + 1) * CHUNKS_PER_B * 4)  // 1.31 MB
#define CO_OFF       ((PF_OFF + PF_BYTES + 255) & ~(size_t)255)
#define CO_BYTES     ((size_t)K1_BLOCKS * 12 * 4)                      // 48 KB
#define EB_OFF       ((CO_OFF + CO_BYTES + 255) & ~(size_t)255)
// edgebuf: [b][row(2)][c(3)][1024] floats = 96 KB

// ---------------------------------------------------------------------------
// K1: classify + per-chunk bin. KEY CHANGE (R11): payloads are scattered into
// a 16 KB LDS buffer at their bin-sorted positions, then written to global
// FULLY LINEARLY (scattered global 16B stores ran at the ~600 GB/s
// scattered-write wall -> ~25 us; linear stream runs at ~6 TB/s).
// ---------------------------------------------------------------------------
__global__ void __launch_bounds__(256)
bin_kernel(const float* __restrict__ uv, const float* __restrict__ pos,
           float4* __restrict__ staged, unsigned* __restrict__ prefix,
           float* __restrict__ corner_out) {
    const int blk   = blockIdx.x;          // 0..1023
    const int b     = blk >> 8;
    const int chunk = blk & (CHUNKS_PER_B - 1);
    const int t     = threadIdx.x;
    const int lane  = t & 63;
    const int wave  = t >> 6;              // 0..3

    __shared__ float4   s_pay[PTS_PER_CHUNK];   // 16 KB sorted payload buffer
    __shared__ unsigned s_hist[512];            // bins 320..511 stay zero
    __shared__ unsigned s_cur[NBINS];
    __shared__ unsigned s_wsum[4];
    __shared__ float    s_corner[12];

    s_hist[t] = 0; s_hist[t + 256] = 0;
    if (t < 12) s_corner[t] = 0.0f;
    __syncthreads();                                               // B1

    const float* uvb = uv  + (size_t)b * 14 * SRC_N;
    const float* pb  = pos + (size_t)b * 3  * SRC_N;
    const int n0 = chunk * PTS_PER_CHUNK + t * 4;

    const float4 pxv = *(const float4*)&pb [n0];
    const float4 pyv = *(const float4*)&pb [SRC_N + n0];
    const float4 ux  = *(const float4*)&uvb[n0];
    const float4 uy  = *(const float4*)&uvb[SRC_N + n0];
    const float4 ov  = *(const float4*)&uvb[10 * SRC_N + n0];
    const float4 rv  = *(const float4*)&uvb[11 * SRC_N + n0];
    const float4 gv  = *(const float4*)&uvb[12 * SRC_N + n0];
    const float4 bv  = *(const float4*)&uvb[13 * SRC_N + n0];

    const float X[4]  = {pxv.x + ux.x, pxv.y + ux.y, pxv.z + ux.z, pxv.w + ux.w};
    const float Y[4]  = {pyv.x + uy.x, pyv.y + uy.y, pyv.z + uy.z, pyv.w + uy.w};
    const float O[4]  = {ov.x, ov.y, ov.z, ov.w};
    const float CR[4] = {rv.x, rv.y, rv.z, rv.w};
    const float CG[4] = {gv.x, gv.y, gv.z, gv.w};
    const float CB[4] = {bv.x, bv.y, bv.z, bv.w};

    unsigned packed[4];
    float R[4], G[4], B[4];

#pragma unroll
    for (int j = 0; j < 4; ++j) {
        // truncating cast (matches .astype(int32)), then clamp
        int px = (int)((X[j] + 1.0f) * 512.0f);
        int py = (int)((Y[j] + 1.0f) * 512.0f);
        px = min(max(px, 0), IMG_W - 1);
        py = min(max(py, 0), IMG_W - 1);

        const float opac = 1.0f / (1.0f + __expf(-O[j]));
        R[j] = CR[j] * opac; G[j] = CG[j] * opac; B[j] = CB[j] * opac;

        const bool xe = (px == 0) | (px == IMG_W - 1);
        const bool ye = (py == 0) | (py == IMG_W - 1);
        if (xe & ye) {
            const int ci = ((py != 0) ? 2 : 0) + ((px != 0) ? 1 : 0);
            atomicAdd(&s_corner[ci * 3 + 0], R[j]);
            atomicAdd(&s_corner[ci * 3 + 1], G[j]);
            atomicAdd(&s_corner[ci * 3 + 2], B[j]);
            packed[j] = SENT;
        } else {
            int bin;
            if (ye) bin = 256 + ((py != 0) ? 32 : 0) + (px >> 5);  // edge seg
            else    bin = py >> 2;                                 // 4-row band
            atomicAdd(&s_hist[bin], 1u);
            packed[j] = ((unsigned)bin << 12) | ((unsigned)(py & 3) << 10)
                      | (unsigned)px;
        }
    }
    __syncthreads();                                               // B2

    // pair-scan: thread t owns bins 2t, 2t+1
    const unsigned h0 = s_hist[2 * t], h1 = s_hist[2 * t + 1];
    const unsigned pair = h0 + h1;
    unsigned incl = pair;
#pragma unroll
    for (int off = 1; off < 64; off <<= 1) {
        const unsigned n = __shfl_up(incl, off, 64);
        if (lane >= off) incl += n;
    }
    if (lane == 63) s_wsum[wave] = incl;   // wave total
    __syncthreads();                                               // B3
    unsigned woff = 0;
#pragma unroll
    for (int w = 0; w < 4; ++w) woff += (w < wave) ? s_wsum[w] : 0u;
    const unsigned excl = woff + incl - pair;

    unsigned* pfT = prefix + (size_t)b * (NBINS + 1) * CHUNKS_PER_B;
    if (t < NBINS / 2) {                   // t < 160: bins 2t, 2t+1
        s_cur[2 * t]     = excl;
        s_cur[2 * t + 1] = excl + h0;
        pfT[(size_t)(2 * t)     * CHUNKS_PER_B + chunk] = excl;
        pfT[(size_t)(2 * t + 1) * CHUNKS_PER_B + chunk] = excl + h0;
    } else if (t == NBINS / 2) {           // bin 320 row = totals
        pfT[(size_t)NBINS * CHUNKS_PER_B + chunk] = excl;
    }
    if (t < 12) corner_out[blk * 12 + t] = s_corner[t];
    __syncthreads();                                               // B4

    // sorted scatter into LDS (cheap random LDS writes)
#pragma unroll
    for (int j = 0; j < 4; ++j) {
        if (packed[j] != SENT) {
            const int bin = packed[j] >> 12;
            const unsigned p = atomicAdd(&s_cur[bin], 1u);
            s_pay[p] = make_float4(__uint_as_float(packed[j]), R[j], G[j], B[j]);
        }
    }
    __syncthreads();                                               // B5

    // fully linear staging store (slots >= total are unread garbage)
    float4* pbase = staged + (size_t)blk * PTS_PER_CHUNK;
#pragma unroll
    for (int k = 0; k < 4; ++k)
        pbase[k * 256 + t] = s_pay[k * 256 + t];
}

// ---------------------------------------------------------------------------
// K2e: one block per (batch, row in {0,1023}, 32-px segment). Contiguous
// run-bound rows; 1 reader per chunk. Accumulates edge payloads + corner
// partials into 96 floats, stores edgebuf.
// ---------------------------------------------------------------------------
__global__ void __launch_bounds__(256)
edge_kernel(const float4* __restrict__ staged, const unsigned* __restrict__ prefix,
            const float* __restrict__ corner_out, float* __restrict__ edgebuf) {
    const int blk = blockIdx.x;            // b*64 + row*32 + seg
    const int b   = blk >> 6;
    const int row = (blk >> 5) & 1;
    const int seg = blk & 31;
    const int bin = 256 + row * 32 + seg;
    const int t   = threadIdx.x;

    __shared__ float acc[96];              // [c][lx]

    if (t < 96) acc[t] = 0.0f;
    const unsigned* pfT = prefix + (size_t)b * (NBINS + 1) * CHUNKS_PER_B;
    const unsigned s = pfT[(size_t)bin       * CHUNKS_PER_B + t];   // contiguous row
    const unsigned e = pfT[(size_t)(bin + 1) * CHUNKS_PER_B + t];   // contiguous row
    __syncthreads();

    const float4* pbase = staged + (size_t)(b * CHUNKS_PER_B + t) * PTS_PER_CHUNK;
    for (unsigned i = s; i < e; ++i) {
        const float4 v = pbase[i];
        const int lx = (int)(__float_as_uint(v.x) & 1023u) - seg * 32;
        atomicAdd(&acc[lx],      v.y);
        atomicAdd(&acc[32 + lx], v.z);
        atomicAdd(&acc[64 + lx], v.w);
    }

    // corner fold: seg 0 owns px=0, seg 31 owns px=1023 of this row
    if ((seg == 0) | (seg == 31)) {
        const int ci = row * 2 + ((seg == 31) ? 1 : 0);
        const int lx = (seg == 31) ? 31 : 0;
        const float* cp = corner_out + (size_t)(b * CHUNKS_PER_B + t) * 12 + ci * 3;
        atomicAdd(&acc[lx],      cp[0]);
        atomicAdd(&acc[32 + lx], cp[1]);
        atomicAdd(&acc[64 + lx], cp[2]);
    }
    __syncthreads();

    if (t < 96) {
        const int c = t >> 5, lx = t & 31;
        edgebuf[((size_t)(b * 2 + row) * 3 + c) * 1024 + seg * 32 + lx] = acc[c * 32 + lx];
    }
}

// ---------------------------------------------------------------------------
// K2: one 512-thread block per (batch, 4-row band). 48 KB LDS stripe.
// Contiguous run-bound rows (1 KB each); 2 sub-readers per chunk.
// LDS-atomic accumulate, fold edgebuf for bands 0/255, fully linear
// nontemporal clipped float4 stores.
// ---------------------------------------------------------------------------
__global__ void __launch_bounds__(512)
accum_kernel(const float4* __restrict__ staged, const unsigned* __restrict__ prefix,
             const float* __restrict__ edgebuf, float* __restrict__ out) {
    const int bg   = blockIdx.x;           // 0..1023
    const int b    = bg >> 8;
    const int band = bg & 255;
    const int t    = threadIdx.x;

    __shared__ float    acc[3 * 4096];     // [c][ly*1024+px], 48 KB
    __shared__ unsigned rs[CHUNKS_PER_B], re[CHUNKS_PER_B];

    float4* acc4 = (float4*)acc;
    const float4 z4 = make_float4(0.f, 0.f, 0.f, 0.f);
#pragma unroll
    for (int i = 0; i < 6; ++i) acc4[i * 512 + t] = z4;
    const unsigned* pfT = prefix + (size_t)b * (NBINS + 1) * CHUNKS_PER_B;
    if (t < 256) rs[t]       = pfT[(size_t)band       * CHUNKS_PER_B + t];
    else         re[t - 256] = pfT[(size_t)(band + 1) * CHUNKS_PER_B + (t - 256)];
    __syncthreads();

    const int chunk = t & 255;
    const int sub   = t >> 8;              // 0..1
    const float4* pbase = staged + (size_t)(b * CHUNKS_PER_B + chunk) * PTS_PER_CHUNK;
    for (unsigned i = rs[chunk] + sub; i < re[chunk]; i += 2) {
        const float4 v = pbase[i];
        const unsigned key = __float_as_uint(v.x);
        const unsigned idx = ((key >> 10) & 3u) * 1024 + (key & 1023u);
        atomicAdd(&acc[idx],        v.y);
        atomicAdd(&acc[4096 + idx], v.z);
        atomicAdd(&acc[8192 + idx], v.w);
    }
    __syncthreads();

    // fold edge rows: band 0 row ly=0 <- edgebuf row0; band 255 ly=3 <- row1023
    if (band == 0) {
        const float4* eb = (const float4*)(edgebuf + (size_t)(b * 2 + 0) * 3 * 1024);
        for (int k = t; k < 768; k += 512) {
            const int c = k >> 8, q = k & 255;
            const float4 e = eb[k];
            float4 a = acc4[c * 1024 + q];            // ly=0 row
            a.x += e.x; a.y += e.y; a.z += e.z; a.w += e.w;
            acc4[c * 1024 + q] = a;
        }
    } else if (band == 255) {
        const float4* eb = (const float4*)(edgebuf + (size_t)(b * 2 + 1) * 3 * 1024);
        for (int k = t; k < 768; k += 512) {
            const int c = k >> 8, q = k & 255;
            const float4 e = eb[k];
            float4 a = acc4[c * 1024 + 768 + q];      // ly=3 row
            a.x += e.x; a.y += e.y; a.z += e.z; a.w += e.w;
            acc4[c * 1024 + 768 + q] = a;
        }
    }
    __syncthreads();

    // fully linear clipped nontemporal stores
    float* ob = out + (size_t)b * 3 * IMG_HW + (size_t)band * 4096;
#pragma unroll
    for (int c = 0; c < 3; ++c) {
        nfloat4* dst = (nfloat4*)(ob + (size_t)c * IMG_HW);
#pragma unroll
        for (int k = 0; k < 2; ++k) {
            float4 v = acc4[c * 1024 + k * 512 + t];
            nfloat4 w;
            w.x = fminf(fmaxf(v.x, 0.f), 1.f);
            w.y = fminf(fmaxf(v.y, 0.f), 1.f);
            w.z = fminf(fmaxf(v.z, 0.f), 1.f);
            w.w = fminf(fmaxf(v.w, 0.f), 1.f);
            __builtin_nontemporal_store(w, &dst[k * 512 + t]);
        }
    }
}

extern "C" void kernel_launch(void* const* d_in, const int* in_sizes, int n_in,
                              void* d_out, int out_size, void* d_ws, size_t ws_size,
                              hipStream_t stream) {
    const float* uv  = (const float*)d_in[0];   // (4,14,512,512)
    const float* pos = (const float*)d_in[1];   // (4,3,512,512)
    float* out = (float*)d_out;                 // (4,3,1024,1024)

    char* ws = (char*)d_ws;
    float4*   staged     = (float4*)(ws);
    unsigned* prefix     = (unsigned*)(ws + PF_OFF);
    float*    corner_out = (float*)(ws + CO_OFF);
    float*    edgebuf    = (float*)(ws + EB_OFF);

    bin_kernel  <<<K1_BLOCKS, K1_THREADS, 0, stream>>>(uv, pos, staged, prefix,
                                                       corner_out);
    edge_kernel <<<BATCH * 64, 256, 0, stream>>>(staged, prefix, corner_out,
                                                 edgebuf);
    accum_kernel<<<BATCH * 256, 512, 0, stream>>>(staged, prefix, edgebuf, out);
}